// Round 1
// 4393.787 us; speedup vs baseline: 1.2762x; 1.2762x over previous
//
#include <hip/hip_runtime.h>
#include <hip/hip_bf16.h>
#include <math.h>

#define NB   128
#define NP   196
#define DENC 2048
#define DDEC 512
#define NV   10000
#define NT   30
#define NTM  29

typedef __attribute__((ext_vector_type(8))) short short8;
typedef __attribute__((ext_vector_type(4))) float f32x4;

__device__ __forceinline__ float sigmoidf_(float x) { return 1.f / (1.f + __expf(-x)); }
__device__ __forceinline__ unsigned short f2bf(float x) {
    unsigned int u = __float_as_uint(x);
    u += 0x7fffu + ((u >> 16) & 1u);   // RNE
    return (unsigned short)(u >> 16);
}
__device__ __forceinline__ float bf2f(unsigned short h) {
    return __uint_as_float(((unsigned int)h) << 16);
}

// ---------------------------------------------------------------------------
// Sort + nt[t] (active prefix length per step)
// ---------------------------------------------------------------------------
__global__ void sort_kernel(const int* __restrict__ len_caps,
                            const int* __restrict__ enc_caps,
                            float* __restrict__ out_caps,
                            float* __restrict__ out_lendec,
                            float* __restrict__ out_order,
                            int* __restrict__ order_ws,
                            int* __restrict__ nt_ws,
                            int* __restrict__ caps_ws) {
    __shared__ int lens[NB];
    int i = threadIdx.x;
    lens[i] = len_caps[i];
    __syncthreads();
    int li = lens[i];
    int r = 0;
    for (int j = 0; j < NB; ++j) {
        int lj = lens[j];
        if (lj > li || (lj == li && j < i)) r++;
    }
    order_ws[r]   = i;
    out_order[r]  = (float)i;
    out_lendec[r] = (float)(li - 1);
    for (int k = 0; k < NT; ++k) {
        int cv = enc_caps[i * NT + k];
        caps_ws[r * NT + k]  = cv;
        out_caps[r * NT + k] = (float)cv;
    }
    if (i < NTM) {
        int cnt = 0;
        for (int j = 0; j < NB; ++j) cnt += (lens[j] - 1 > i) ? 1 : 0;
        nt_ws[i] = cnt;
    }
}

__global__ void rowmap_kernel(const int* __restrict__ order, int* __restrict__ rowmap) {
    int m = blockIdx.x * 256 + threadIdx.x;
    rowmap[m] = order[m / NP] * NP + (m % NP);
}

__global__ void mu_kernel(const float* __restrict__ enc,
                          const int* __restrict__ order,
                          float* __restrict__ mu) {
    int b = blockIdx.x;
    int d = blockIdx.y * 256 + threadIdx.x;
    const float* eb = enc + (long)order[b] * NP * DENC;
    float s = 0.f;
    for (int p = 0; p < NP; ++p) s += eb[(long)p * DENC + d];
    mu[(long)b * DENC + d] = s * (1.f / (float)NP);
}

__global__ void fill_zero4(float4* __restrict__ p, int n4) {
    int i = blockIdx.x * 256 + threadIdx.x;
    if (i < n4) p[i] = make_float4(0.f, 0.f, 0.f, 0.f);
}

__global__ void conv_bf(const float* __restrict__ s, unsigned short* __restrict__ d, int n) {
    int i = blockIdx.x * 256 + threadIdx.x;
    if (i < n) d[i] = f2bf(s[i]);
}

// W_ihh[n][k] = k<2560 ? W_ih[n][k] : W_hh[n][k-2560]; grid (12, 2048)
__global__ void kconcat_ihh(const float* __restrict__ W_ih, const float* __restrict__ W_hh,
                            unsigned short* __restrict__ dst) {
    int n = blockIdx.y;
    int k = blockIdx.x * 256 + threadIdx.x;   // < 3072
    float v = (k < 2560) ? W_ih[(long)n * 2560 + k] : W_hh[(long)n * 512 + (k - 2560)];
    dst[(long)n * 3072 + k] = f2bf(v);
}

__global__ void bias_add2(const float* __restrict__ a, const float* __restrict__ b,
                          float* __restrict__ d, int n) {
    int i = blockIdx.x * 256 + threadIdx.x;
    if (i < n) d[i] = a[i] + b[i];
}

// ---------------------------------------------------------------------------
// bf16 MFMA GEMM: out[m][n] = act(A[m][:].W[n][:] + bias[n])
// BM=64 BN=128 BK=32; 256 thr = 4 waves (2x2), wave tile 32x64 (2x4 frags of
// 16x16x32). A fp32 (converted in staging), W bf16 (N x K row-major).
// Two output segments split at column `split` (separate ptr/bias/act), or
// bf16 output via outbf. Row limit nt[t] (active-prefix pruning).
// blockIdx.z = K-chunk: A/W advanced by z*K, out0 advanced by z*zstride
// (partials reduced by consumer). bias pointers may be null (-> 0).
// Non-pruned launches (nt==nullptr) get an XCD-chunked bijective block
// swizzle so n-blocks sharing an A-panel land on one XCD's L2.
// ---------------------------------------------------------------------------
__global__ __launch_bounds__(256) void gemm_mfma(
    const float* __restrict__ A, long lda, const int* __restrict__ rowmap,
    const unsigned short* __restrict__ W, long ldw,
    const float* __restrict__ bias0, const float* __restrict__ bias1, int split,
    float* __restrict__ out0, long ld0, float* __restrict__ out1, long ld1,
    unsigned short* __restrict__ outbf,
    int act0, int act1, int M, int N, int K,
    const int* __restrict__ nt, int t, long zstride) {
    __shared__ __align__(16) unsigned short As[64 * 32];
    __shared__ __align__(16) unsigned short Bs[128 * 32];
    const int limit = nt ? nt[t] : M;

    int bx = blockIdx.x, by = blockIdx.y;
    if (!nt) {
        // bijective XCD-chunked swizzle (8 XCDs): consecutive sw share by
        int nwg = gridDim.x * gridDim.y;
        int lin = by * gridDim.x + bx;
        int q = nwg >> 3, r = nwg & 7;
        int xcd = lin & 7, i = lin >> 3;
        int sw = (xcd < r ? xcd * (q + 1) : r * (q + 1) + (xcd - r) * q) + i;
        bx = sw % gridDim.x;
        by = sw / gridDim.x;
    }

    const int m0 = by * 64;
    if (m0 >= limit) return;
    const int n0 = bx * 128;
    const int tid = threadIdx.x;
    const int kz = blockIdx.z * K;

    // staging addressing
    const int arow = tid >> 2, ak = (tid & 3) * 8;
    const int brow = tid >> 1, bk = (tid & 1) * 16;
    long aRowG = m0 + arow;
    if (rowmap) aRowG = rowmap[aRowG];
    const float* aptr = A + aRowG * lda + ak + kz;
    const int gnw = n0 + brow;
    const bool wvalid = gnw < N;
    const unsigned short* wptr = W + (long)(wvalid ? gnw : 0) * ldw + bk + kz;

    if (blockIdx.z) out0 += (long)blockIdx.z * zstride;

    // fragment addressing
    const int lane = tid & 63, wv = tid >> 6;
    const int wm = wv & 1, wn = wv >> 1;
    const int fcol = lane & 15, quad = lane >> 4;
    const unsigned short* aFp = As + ((wm * 32 + fcol) * 32 + quad * 8);
    const unsigned short* bFp = Bs + ((wn * 64 + fcol) * 32 + quad * 8);

    f32x4 acc[2][4];
#pragma unroll
    for (int i = 0; i < 2; ++i)
#pragma unroll
        for (int j = 0; j < 4; ++j) acc[i][j] = (f32x4){0.f, 0.f, 0.f, 0.f};

    for (int k0 = 0; k0 < K; k0 += 32) {
        float4 x0 = *(const float4*)(aptr);
        float4 x1 = *(const float4*)(aptr + 4);
        aptr += 32;
        int4 w0 = make_int4(0, 0, 0, 0), w1 = w0;
        if (wvalid) {
            w0 = *(const int4*)(wptr);
            w1 = *(const int4*)(wptr + 8);
        }
        wptr += 32;
        short8 ap;
        ap[0] = (short)f2bf(x0.x); ap[1] = (short)f2bf(x0.y);
        ap[2] = (short)f2bf(x0.z); ap[3] = (short)f2bf(x0.w);
        ap[4] = (short)f2bf(x1.x); ap[5] = (short)f2bf(x1.y);
        ap[6] = (short)f2bf(x1.z); ap[7] = (short)f2bf(x1.w);
        __syncthreads();   // previous iteration's reads done
        *(short8*)(As + (arow * 32 + ak)) = ap;
        *(int4*)(Bs + (brow * 32 + bk)) = w0;
        *(int4*)(Bs + (brow * 32 + bk + 8)) = w1;
        __syncthreads();
        short8 a0 = *(const short8*)(aFp);
        short8 a1 = *(const short8*)(aFp + 512);
#pragma unroll
        for (int ns = 0; ns < 4; ++ns) {
            short8 bn = *(const short8*)(bFp + ns * 512);
            acc[0][ns] = __builtin_amdgcn_mfma_f32_16x16x32_bf16(a0, bn, acc[0][ns], 0, 0, 0);
            acc[1][ns] = __builtin_amdgcn_mfma_f32_16x16x32_bf16(a1, bn, acc[1][ns], 0, 0, 0);
        }
    }

    // epilogue: C/D layout col=lane&15, row=quad*4+reg
#pragma unroll
    for (int ms = 0; ms < 2; ++ms) {
        int gmb = m0 + wm * 32 + ms * 16 + quad * 4;
#pragma unroll
        for (int ns = 0; ns < 4; ++ns) {
            int gn = n0 + wn * 64 + ns * 16 + fcol;
            if (gn >= N) continue;
            int seg = (gn >= split);
            float bv = seg ? (bias1 ? bias1[gn - split] : 0.f)
                           : (bias0 ? bias0[gn] : 0.f);
            int act = seg ? act1 : act0;
#pragma unroll
            for (int r = 0; r < 4; ++r) {
                int gm = gmb + r;
                if (gm >= limit) continue;
                float v = acc[ms][ns][r] + bv;
                if (act == 1) v = sigmoidf_(v);
                if (outbf) outbf[(long)gm * ld0 + gn] = f2bf(v);
                else if (!seg) out0[(long)gm * ld0 + gn] = v;
                else out1[(long)gm * ld1 + (gn - split)] = v;
            }
        }
    }
}

// ---------------------------------------------------------------------------
// alpha_kernel: e = relu(att_enc + att_dec) . W_att + b; softmax -> al_g,
// out_alpha. Also fills xh's emb part (cols 0..511) and h part (2560..3071).
// Grid (NB), 256 thr. Pruned by nt[t].
// ---------------------------------------------------------------------------
__global__ __launch_bounds__(256) void alpha_kernel(
    const unsigned short* __restrict__ att_enc,   // bf16 [B*196][512]
    const float* __restrict__ adg,                // [B][2560], cols 0..511 = att_dec
    const float* __restrict__ W_att, const float* __restrict__ b_att,
    const float* __restrict__ emb, const int* __restrict__ caps,
    const float* __restrict__ h,
    const int* __restrict__ nt,
    float* __restrict__ al_g,                     // [B][196]
    float* __restrict__ out_alpha,
    float* __restrict__ xh, int t) {
    int b = blockIdx.x;
    if (b >= nt[t]) return;
    int tid = threadIdx.x, lane = tid & 63, wid = tid >> 6;
    __shared__ float es[NP];
    __shared__ float stats[2];

    // lane-private att_dec & W_att slices (d = lane*8 .. +7)
    const float* adp = adg + (long)b * 2560 + lane * 8;
    float4 ad0 = *(const float4*)(adp);
    float4 ad1 = *(const float4*)(adp + 4);
    const float* wap = W_att + lane * 8;
    float4 wa0 = *(const float4*)(wap);
    float4 wa1 = *(const float4*)(wap + 4);
    float ad[8] = {ad0.x, ad0.y, ad0.z, ad0.w, ad1.x, ad1.y, ad1.z, ad1.w};
    float wa[8] = {wa0.x, wa0.y, wa0.z, wa0.w, wa1.x, wa1.y, wa1.z, wa1.w};
    float batt = b_att[0];

    for (int p = wid; p < NP; p += 4) {
        const unsigned short* row = att_enc + ((long)b * NP + p) * 512 + lane * 8;
        int4 rv = *(const int4*)row;
        const unsigned short* us = (const unsigned short*)&rv;
        float s = 0.f;
#pragma unroll
        for (int j = 0; j < 8; ++j) {
            float v = bf2f(us[j]) + ad[j];
            v = v > 0.f ? v : 0.f;
            s += v * wa[j];
        }
#pragma unroll
        for (int o = 32; o; o >>= 1) s += __shfl_xor(s, o, 64);
        if (lane == 0) es[p] = s + batt;
    }
    __syncthreads();
    if (wid == 0) {
        float v[4], mx = -1e30f;
#pragma unroll
        for (int i = 0; i < 4; ++i) {
            int p = lane + 64 * i;
            v[i] = (p < NP) ? es[p] : -1e30f;
            mx = fmaxf(mx, v[i]);
        }
#pragma unroll
        for (int o = 32; o; o >>= 1) mx = fmaxf(mx, __shfl_xor(mx, o, 64));
        float s = 0.f;
#pragma unroll
        for (int i = 0; i < 4; ++i) {
            int p = lane + 64 * i;
            if (p < NP) s += __expf(v[i] - mx);
        }
#pragma unroll
        for (int o = 32; o; o >>= 1) s += __shfl_xor(s, o, 64);
        if (lane == 0) { stats[0] = mx; stats[1] = 1.f / s; }
    }
    __syncthreads();
    float mm = stats[0], inv = stats[1];
    if (tid < NP) {
        float a = __expf(es[tid] - mm) * inv;
        al_g[(long)b * NP + tid] = a;
        out_alpha[((long)b * NTM + t) * NP + tid] = a;
    }
    // xh extras: emb part and h part (2 floats each per thread)
    int cap = caps[b * NT + t];
    float2 ev = *(const float2*)(emb + (long)cap * 512 + tid * 2);
    *(float2*)(xh + (long)b * 3072 + tid * 2) = ev;
    float2 hv = *(const float2*)(h + (long)b * DDEC + tid * 2);
    *(float2*)(xh + (long)b * 3072 + 2560 + tid * 2) = hv;
}

// ---------------------------------------------------------------------------
// wx_kernel: xh[b][512+d] = (sum_p al[p]*enc[p][d]) * gate[d]
// Grid (NB, 8) -> 256-col slices; 256 thr, 1 col each. Pruned by nt[t].
// ---------------------------------------------------------------------------
__global__ __launch_bounds__(256) void wx_kernel(
    const float* __restrict__ al_g,
    const float* __restrict__ adg,                // gate at [b][512+d]
    const float* __restrict__ enc, const int* __restrict__ order,
    const int* __restrict__ nt,
    float* __restrict__ xh, int t) {
    int b = blockIdx.x;
    if (b >= nt[t]) return;
    int d = blockIdx.y * 256 + threadIdx.x;   // < 2048
    __shared__ float al[NP];
    if (threadIdx.x < NP) al[threadIdx.x] = al_g[(long)b * NP + threadIdx.x];
    __syncthreads();
    const float* eb = enc + ((long)order[b] * NP) * DENC + d;
    float acc = 0.f;
#pragma unroll 4
    for (int p = 0; p < NP; ++p) acc += al[p] * eb[(long)p * DENC];
    float gate = adg[(long)b * 2560 + 512 + d];
    xh[(long)b * 3072 + 512 + d] = acc * gate;
}

// LSTM pointwise: sum 3 K-chunk partials + bias, update h,c. grid (2, NB)
__global__ void lstm_kernel(const float* __restrict__ gp,
                            const float* __restrict__ bihh,
                            float* __restrict__ c,
                            float* __restrict__ h,
                            const int* __restrict__ nt, int t) {
    int b = blockIdx.y;
    if (b >= nt[t]) return;
    int d = blockIdx.x * 256 + threadIdx.x;   // < 512
    const long S = (long)NB * 2048;
    const float* g = gp + ((long)b << 11);
    float ig = sigmoidf_(g[d]        + g[S + d]        + g[2*S + d]        + bihh[d]);
    float fg = sigmoidf_(g[512 + d]  + g[S + 512 + d]  + g[2*S + 512 + d]  + bihh[512 + d]);
    float gg = tanhf(    g[1024 + d] + g[S + 1024 + d] + g[2*S + 1024 + d] + bihh[1024 + d]);
    float og = sigmoidf_(g[1536 + d] + g[S + 1536 + d] + g[2*S + 1536 + d] + bihh[1536 + d]);
    long idx = (long)b * DDEC + d;
    float cn = fg * c[idx] + ig * gg;
    c[idx] = cn;
    h[idx] = og * tanhf(cn);
}

// ---------------------------------------------------------------------------
extern "C" void kernel_launch(void* const* d_in, const int* in_sizes, int n_in,
                              void* d_out, int out_size, void* d_ws, size_t ws_size,
                              hipStream_t stream) {
    const float* enc_out   = (const float*)d_in[0];
    const int*   enc_caps  = (const int*)d_in[1];
    const int*   len_caps  = (const int*)d_in[2];
    const float* emb       = (const float*)d_in[3];
    const float* W_enc_att = (const float*)d_in[4];
    const float* b_enc_att = (const float*)d_in[5];
    const float* W_dec_att = (const float*)d_in[6];
    const float* b_dec_att = (const float*)d_in[7];
    const float* W_att     = (const float*)d_in[8];
    const float* b_att     = (const float*)d_in[9];
    const float* W_init_h  = (const float*)d_in[10];
    const float* b_init_h  = (const float*)d_in[11];
    const float* W_init_c  = (const float*)d_in[12];
    const float* b_init_c  = (const float*)d_in[13];
    const float* W_ih      = (const float*)d_in[14];
    const float* b_ih      = (const float*)d_in[15];
    const float* W_hh      = (const float*)d_in[16];
    const float* b_hh      = (const float*)d_in[17];
    const float* W_fbeta   = (const float*)d_in[18];
    const float* b_fbeta   = (const float*)d_in[19];
    const float* W_fc      = (const float*)d_in[20];
    const float* b_fc      = (const float*)d_in[21];

    float* out        = (float*)d_out;
    float* out_caps   = out;
    float* out_lendec = out + 3840;
    float* out_pred   = out + 3968;
    float* out_alpha  = out + 3968 + 37120000;
    float* out_order  = out + 3968 + 37120000 + 727552;

    char*  wsb = (char*)d_ws;
    size_t off = 0;
    auto alloc = [&](size_t bytes) -> void* {
        void* p = wsb + off;
        off += (bytes + 255) & ~(size_t)255;
        return p;
    };
    int*   order_ws = (int*)alloc(NB * 4);
    int*   nt_ws    = (int*)alloc(NTM * 4);
    int*   caps_ws  = (int*)alloc(NB * NT * 4);
    int*   rowmap   = (int*)alloc((size_t)NB * NP * 4);
    float* mu       = (float*)alloc((size_t)NB * DENC * 4);
    float* h        = (float*)alloc((size_t)NB * DDEC * 4);
    float* c        = (float*)alloc((size_t)NB * DDEC * 4);
    float* adg      = (float*)alloc((size_t)NB * 2560 * 4);
    float* al_g     = (float*)alloc((size_t)NB * NP * 4);
    float* xh       = (float*)alloc((size_t)NB * 3072 * 4);
    float* gates    = (float*)alloc((size_t)3 * NB * 2048 * 4);   // 3 K-chunk partials
    unsigned short* att_enc_bf = (unsigned short*)alloc((size_t)NB * NP * 512 * 2);
    unsigned short* Wq_enc  = (unsigned short*)alloc((size_t)512 * 2048 * 2);
    unsigned short* Wq_init = (unsigned short*)alloc((size_t)1024 * 2048 * 2);
    unsigned short* Wq_adg  = (unsigned short*)alloc((size_t)2560 * 512 * 2);
    unsigned short* Wq_ihh  = (unsigned short*)alloc((size_t)2048 * 3072 * 2);
    unsigned short* Wq_fc   = (unsigned short*)alloc((size_t)NV * 512 * 2);
    float* bihh = (float*)alloc(2048 * 4);

    // ---- prologue ----
    sort_kernel<<<1, NB, 0, stream>>>(len_caps, enc_caps, out_caps, out_lendec,
                                      out_order, order_ws, nt_ws, caps_ws);
    fill_zero4<<<36960, 256, 0, stream>>>((float4*)out_pred, 9461888);  // preds+alphas
    rowmap_kernel<<<98, 256, 0, stream>>>(order_ws, rowmap);
    mu_kernel<<<dim3(NB, DENC / 256), 256, 0, stream>>>(enc_out, order_ws, mu);

    conv_bf<<<(512 * 2048) / 256, 256, 0, stream>>>(W_enc_att, Wq_enc, 512 * 2048);
    conv_bf<<<(512 * 2048) / 256, 256, 0, stream>>>(W_init_h, Wq_init, 512 * 2048);
    conv_bf<<<(512 * 2048) / 256, 256, 0, stream>>>(W_init_c, Wq_init + (size_t)512 * 2048, 512 * 2048);
    conv_bf<<<(512 * 512) / 256, 256, 0, stream>>>(W_dec_att, Wq_adg, 512 * 512);
    conv_bf<<<(2048 * 512) / 256, 256, 0, stream>>>(W_fbeta, Wq_adg + (size_t)512 * 512, 2048 * 512);
    kconcat_ihh<<<dim3(12, 2048), 256, 0, stream>>>(W_ih, W_hh, Wq_ihh);
    conv_bf<<<(NV * 512) / 256, 256, 0, stream>>>(W_fc, Wq_fc, NV * 512);
    bias_add2<<<8, 256, 0, stream>>>(b_ih, b_hh, bihh, 2048);

    // h|c init: A=mu, W=Wq_init [1024][2048], split at 512
    gemm_mfma<<<dim3(8, 2), 256, 0, stream>>>(
        mu, DENC, nullptr, Wq_init, DENC,
        b_init_h, b_init_c, 512,
        h, DDEC, c, DDEC, nullptr, 0, 0,
        NB, 1024, DENC, nullptr, 0, 0);

    // att_enc (bf16 out): A=enc via rowmap, W=Wq_enc [512][2048]
    gemm_mfma<<<dim3(4, 392), 256, 0, stream>>>(
        enc_out, DENC, rowmap, Wq_enc, DENC,
        b_enc_att, nullptr, 512,
        nullptr, 512, nullptr, 0, att_enc_bf, 0, 0,
        NB * NP, 512, DENC, nullptr, 0, 0);

    // ---- time loop ----
    for (int t = 0; t < NTM; ++t) {
        // adg = [att_dec | sigmoid(gate)]: A=h, W=Wq_adg [2560][512]
        gemm_mfma<<<dim3(20, 2), 256, 0, stream>>>(
            h, DDEC, nullptr, Wq_adg, DDEC,
            b_dec_att, b_fbeta, 512,
            adg, 2560, adg + 512, 2560, nullptr, 0, 1,
            NB, 2560, DDEC, nt_ws, t, 0);
        // e + softmax -> al_g/out_alpha; also fills xh emb & h parts
        alpha_kernel<<<NB, 256, 0, stream>>>(
            att_enc_bf, adg, W_att, b_att, emb, caps_ws, h, nt_ws,
            al_g, out_alpha, xh, t);
        // xh middle: weighted*gate, 8-way column split
        wx_kernel<<<dim3(NB, 8), 256, 0, stream>>>(
            al_g, adg, enc_out, order_ws, nt_ws, xh, t);
        // gates partials = xh @ Wq_ihh^T, split-K x3 (K=1024 per chunk)
        gemm_mfma<<<dim3(16, 2, 3), 256, 0, stream>>>(
            xh, 3072, nullptr, Wq_ihh, 3072,
            nullptr, nullptr, 2048,
            gates, 2048, nullptr, 0, nullptr, 0, 0,
            NB, 2048, 1024, nt_ws, t, (long)NB * 2048);
        // LSTM pointwise (sums partials + bias)
        lstm_kernel<<<dim3(2, NB), 256, 0, stream>>>(gates, bihh, c, h, nt_ws, t);
        // preds = h @ Wq_fc^T (active rows only; rest pre-zeroed)
        gemm_mfma<<<dim3(79, 2), 256, 0, stream>>>(
            h, DDEC, nullptr, Wq_fc, DDEC,
            b_fc, nullptr, NV,
            out_pred + (long)t * NV, (long)NTM * NV, nullptr, 0, nullptr, 0, 0,
            NB, NV, DDEC, nt_ws, t, 0);
    }
}

// Round 2
// 4085.709 us; speedup vs baseline: 1.3725x; 1.0754x over previous
//
#include <hip/hip_runtime.h>
#include <hip/hip_bf16.h>
#include <math.h>

#define NB   128
#define NP   196
#define DENC 2048
#define DDEC 512
#define NV   10000
#define NT   30
#define NTM  29

typedef __attribute__((ext_vector_type(8))) short short8;
typedef __attribute__((ext_vector_type(4))) float f32x4;

__device__ __forceinline__ float sigmoidf_(float x) { return 1.f / (1.f + __expf(-x)); }
__device__ __forceinline__ unsigned short f2bf(float x) {
    unsigned int u = __float_as_uint(x);
    u += 0x7fffu + ((u >> 16) & 1u);   // RNE
    return (unsigned short)(u >> 16);
}
__device__ __forceinline__ float bf2f(unsigned short h) {
    return __uint_as_float(((unsigned int)h) << 16);
}

// ---------------------------------------------------------------------------
// Sort + nt[t] (active prefix length per step)
// ---------------------------------------------------------------------------
__global__ void sort_kernel(const int* __restrict__ len_caps,
                            const int* __restrict__ enc_caps,
                            float* __restrict__ out_caps,
                            float* __restrict__ out_lendec,
                            float* __restrict__ out_order,
                            int* __restrict__ order_ws,
                            int* __restrict__ nt_ws,
                            int* __restrict__ caps_ws) {
    __shared__ int lens[NB];
    int i = threadIdx.x;
    lens[i] = len_caps[i];
    __syncthreads();
    int li = lens[i];
    int r = 0;
    for (int j = 0; j < NB; ++j) {
        int lj = lens[j];
        if (lj > li || (lj == li && j < i)) r++;
    }
    order_ws[r]   = i;
    out_order[r]  = (float)i;
    out_lendec[r] = (float)(li - 1);
    for (int k = 0; k < NT; ++k) {
        int cv = enc_caps[i * NT + k];
        caps_ws[r * NT + k]  = cv;
        out_caps[r * NT + k] = (float)cv;
    }
    if (i < NTM) {
        int cnt = 0;
        for (int j = 0; j < NB; ++j) cnt += (lens[j] - 1 > i) ? 1 : 0;
        nt_ws[i] = cnt;
    }
}

__global__ void rowmap_kernel(const int* __restrict__ order, int* __restrict__ rowmap) {
    int m = blockIdx.x * 256 + threadIdx.x;
    rowmap[m] = order[m / NP] * NP + (m % NP);
}

__global__ void mu_kernel(const float* __restrict__ enc,
                          const int* __restrict__ order,
                          float* __restrict__ mu) {
    int b = blockIdx.x;
    int d = blockIdx.y * 256 + threadIdx.x;
    const float* eb = enc + (long)order[b] * NP * DENC;
    float s = 0.f;
    for (int p = 0; p < NP; ++p) s += eb[(long)p * DENC + d];
    mu[(long)b * DENC + d] = s * (1.f / (float)NP);
}

__global__ void fill_zero4(float4* __restrict__ p, int n4) {
    int i = blockIdx.x * 256 + threadIdx.x;
    if (i < n4) p[i] = make_float4(0.f, 0.f, 0.f, 0.f);
}

__global__ void conv_bf(const float* __restrict__ s, unsigned short* __restrict__ d, int n) {
    int i = blockIdx.x * 256 + threadIdx.x;
    if (i < n) d[i] = f2bf(s[i]);
}

// W_ihh[n][k] = k<2560 ? W_ih[n][k] : W_hh[n][k-2560]; grid (12, 2048)
__global__ void kconcat_ihh(const float* __restrict__ W_ih, const float* __restrict__ W_hh,
                            unsigned short* __restrict__ dst) {
    int n = blockIdx.y;
    int k = blockIdx.x * 256 + threadIdx.x;   // < 3072
    float v = (k < 2560) ? W_ih[(long)n * 2560 + k] : W_hh[(long)n * 512 + (k - 2560)];
    dst[(long)n * 3072 + k] = f2bf(v);
}

__global__ void bias_add2(const float* __restrict__ a, const float* __restrict__ b,
                          float* __restrict__ d, int n) {
    int i = blockIdx.x * 256 + threadIdx.x;
    if (i < n) d[i] = a[i] + b[i];
}

// ---------------------------------------------------------------------------
// bf16 MFMA GEMM: out[m][n] = act(A[m][:].W[n][:] + bias[n])
// BM=64 BN=128 BK=32; 256 thr = 4 waves (2x2), wave tile 32x64 (2x4 frags of
// 16x16x32). A fp32 (abf=0, converted in staging) or bf16 (abf=1).
// W bf16 (N x K row-major).
// LDS tiles XOR-swizzled at 16B-chunk granularity: chunk ^= (row>>1)&3,
// applied identically on write and read -> uniform bank-group spread
// (SQ_LDS_BANK_CONFLICT ~0 vs 1.6e7 for linear layout).
// Output: two fp32 segments split at `split`, or outbf (bf16) for seg0 with
// fp32 out1 for seg1. Row limit nt[t]. blockIdx.z = K-chunk (partials).
// Non-pruned launches get a bijective XCD-chunked block swizzle.
// ---------------------------------------------------------------------------
__global__ __launch_bounds__(256) void gemm_mfma(
    const float* __restrict__ A, long lda, const int* __restrict__ rowmap,
    const unsigned short* __restrict__ W, long ldw,
    const float* __restrict__ bias0, const float* __restrict__ bias1, int split,
    float* __restrict__ out0, long ld0, float* __restrict__ out1, long ld1,
    unsigned short* __restrict__ outbf,
    int act0, int act1, int M, int N, int K,
    const int* __restrict__ nt, int t, long zstride, int abf) {
    __shared__ __align__(16) unsigned short As[64 * 32];
    __shared__ __align__(16) unsigned short Bs[128 * 32];
    const int limit = nt ? nt[t] : M;

    int bx = blockIdx.x, by = blockIdx.y;
    if (!nt) {
        // bijective XCD-chunked swizzle (8 XCDs): consecutive sw share by
        int nwg = gridDim.x * gridDim.y;
        int lin = by * gridDim.x + bx;
        int q = nwg >> 3, r = nwg & 7;
        int xcd = lin & 7, i = lin >> 3;
        int sw = (xcd < r ? xcd * (q + 1) : r * (q + 1) + (xcd - r) * q) + i;
        bx = sw % gridDim.x;
        by = sw / gridDim.x;
    }

    const int m0 = by * 64;
    if (m0 >= limit) return;
    const int n0 = bx * 128;
    const int tid = threadIdx.x;
    const int kz = blockIdx.z * K;

    // staging addressing (akc/bkc = 16B chunk indices within a 64B row)
    const int arow = tid >> 2, akc = tid & 3;
    const int aws = (akc ^ ((arow >> 1) & 3)) * 8;      // swizzled short offset
    const int brow = tid >> 1, bkc = (tid & 1) * 2;
    const int bss = (brow >> 1) & 3;
    const int bws0 = (bkc ^ bss) * 8;
    const int bws1 = ((bkc + 1) ^ bss) * 8;

    long aRowG = m0 + arow;
    if (rowmap) aRowG = rowmap[aRowG];
    const float* aptrf = nullptr;
    const unsigned short* aptrh = nullptr;
    if (abf) aptrh = (const unsigned short*)A + aRowG * lda + akc * 8 + kz;
    else     aptrf = A + aRowG * lda + akc * 8 + kz;
    const int gnw = n0 + brow;
    const bool wvalid = gnw < N;
    const unsigned short* wptr = W + (long)(wvalid ? gnw : 0) * ldw + bkc * 8 + kz;

    if (blockIdx.z) out0 += (long)blockIdx.z * zstride;

    // fragment addressing (read-side swizzle: same XOR as write side)
    const int lane = tid & 63, wv = tid >> 6;
    const int wm = wv & 1, wn = wv >> 1;
    const int fcol = lane & 15, quad = lane >> 4;
    const int sx = (fcol >> 1) & 3;                      // (row>>1)&3 for row=..+fcol
    const unsigned short* aFp = As + ((wm * 32 + fcol) * 32 + ((quad ^ sx) * 8));
    const unsigned short* bFp = Bs + ((wn * 64 + fcol) * 32 + ((quad ^ sx) * 8));

    f32x4 acc[2][4];
#pragma unroll
    for (int i = 0; i < 2; ++i)
#pragma unroll
        for (int j = 0; j < 4; ++j) acc[i][j] = (f32x4){0.f, 0.f, 0.f, 0.f};

    for (int k0 = 0; k0 < K; k0 += 32) {
        short8 ap;
        if (abf) {
            ap = *(const short8*)(aptrh);
            aptrh += 32;
        } else {
            float4 x0 = *(const float4*)(aptrf);
            float4 x1 = *(const float4*)(aptrf + 4);
            aptrf += 32;
            ap[0] = (short)f2bf(x0.x); ap[1] = (short)f2bf(x0.y);
            ap[2] = (short)f2bf(x0.z); ap[3] = (short)f2bf(x0.w);
            ap[4] = (short)f2bf(x1.x); ap[5] = (short)f2bf(x1.y);
            ap[6] = (short)f2bf(x1.z); ap[7] = (short)f2bf(x1.w);
        }
        int4 w0 = make_int4(0, 0, 0, 0), w1 = w0;
        if (wvalid) {
            w0 = *(const int4*)(wptr);
            w1 = *(const int4*)(wptr + 8);
        }
        wptr += 32;
        __syncthreads();   // previous iteration's reads done
        *(short8*)(As + (arow * 32 + aws)) = ap;
        *(int4*)(Bs + (brow * 32 + bws0)) = w0;
        *(int4*)(Bs + (brow * 32 + bws1)) = w1;
        __syncthreads();
        short8 a0 = *(const short8*)(aFp);
        short8 a1 = *(const short8*)(aFp + 512);
#pragma unroll
        for (int ns = 0; ns < 4; ++ns) {
            short8 bn = *(const short8*)(bFp + ns * 512);
            acc[0][ns] = __builtin_amdgcn_mfma_f32_16x16x32_bf16(a0, bn, acc[0][ns], 0, 0, 0);
            acc[1][ns] = __builtin_amdgcn_mfma_f32_16x16x32_bf16(a1, bn, acc[1][ns], 0, 0, 0);
        }
    }

    // epilogue: C/D layout col=lane&15, row=quad*4+reg
#pragma unroll
    for (int ms = 0; ms < 2; ++ms) {
        int gmb = m0 + wm * 32 + ms * 16 + quad * 4;
#pragma unroll
        for (int ns = 0; ns < 4; ++ns) {
            int gn = n0 + wn * 64 + ns * 16 + fcol;
            if (gn >= N) continue;
            int seg = (gn >= split);
            float bv = seg ? (bias1 ? bias1[gn - split] : 0.f)
                           : (bias0 ? bias0[gn] : 0.f);
            int act = seg ? act1 : act0;
#pragma unroll
            for (int r = 0; r < 4; ++r) {
                int gm = gmb + r;
                if (gm >= limit) continue;
                float v = acc[ms][ns][r] + bv;
                if (act == 1) v = sigmoidf_(v);
                if (outbf && !seg) outbf[(long)gm * ld0 + gn] = f2bf(v);
                else if (!seg) out0[(long)gm * ld0 + gn] = v;
                else out1[(long)gm * ld1 + (gn - split)] = v;
            }
        }
    }
}

// ---------------------------------------------------------------------------
// alpha_kernel: e = relu(att_enc + att_dec) . W_att + b; softmax -> al_g,
// out_alpha. Also fills xh's emb part (cols 0..511, bf16) and h part
// (2560..3071, bf16 copy). Grid (NB), 256 thr. Pruned by nt[t].
// ---------------------------------------------------------------------------
__global__ __launch_bounds__(256) void alpha_kernel(
    const unsigned short* __restrict__ att_enc,   // bf16 [B*196][512]
    const float* __restrict__ adg,                // [B][2560], cols 0..511 = att_dec
    const float* __restrict__ W_att, const float* __restrict__ b_att,
    const float* __restrict__ emb, const int* __restrict__ caps,
    const unsigned short* __restrict__ h_bf,
    const int* __restrict__ nt,
    float* __restrict__ al_g,                     // [B][196]
    float* __restrict__ out_alpha,
    unsigned short* __restrict__ xh, int t) {
    int b = blockIdx.x;
    if (b >= nt[t]) return;
    int tid = threadIdx.x, lane = tid & 63, wid = tid >> 6;
    __shared__ float es[NP];
    __shared__ float stats[2];

    // lane-private att_dec & W_att slices (d = lane*8 .. +7)
    const float* adp = adg + (long)b * 2560 + lane * 8;
    float4 ad0 = *(const float4*)(adp);
    float4 ad1 = *(const float4*)(adp + 4);
    const float* wap = W_att + lane * 8;
    float4 wa0 = *(const float4*)(wap);
    float4 wa1 = *(const float4*)(wap + 4);
    float ad[8] = {ad0.x, ad0.y, ad0.z, ad0.w, ad1.x, ad1.y, ad1.z, ad1.w};
    float wa[8] = {wa0.x, wa0.y, wa0.z, wa0.w, wa1.x, wa1.y, wa1.z, wa1.w};
    float batt = b_att[0];

    for (int p = wid; p < NP; p += 4) {
        const unsigned short* row = att_enc + ((long)b * NP + p) * 512 + lane * 8;
        int4 rv = *(const int4*)row;
        const unsigned short* us = (const unsigned short*)&rv;
        float s = 0.f;
#pragma unroll
        for (int j = 0; j < 8; ++j) {
            float v = bf2f(us[j]) + ad[j];
            v = v > 0.f ? v : 0.f;
            s += v * wa[j];
        }
#pragma unroll
        for (int o = 32; o; o >>= 1) s += __shfl_xor(s, o, 64);
        if (lane == 0) es[p] = s + batt;
    }
    __syncthreads();
    if (wid == 0) {
        float v[4], mx = -1e30f;
#pragma unroll
        for (int i = 0; i < 4; ++i) {
            int p = lane + 64 * i;
            v[i] = (p < NP) ? es[p] : -1e30f;
            mx = fmaxf(mx, v[i]);
        }
#pragma unroll
        for (int o = 32; o; o >>= 1) mx = fmaxf(mx, __shfl_xor(mx, o, 64));
        float s = 0.f;
#pragma unroll
        for (int i = 0; i < 4; ++i) {
            int p = lane + 64 * i;
            if (p < NP) s += __expf(v[i] - mx);
        }
#pragma unroll
        for (int o = 32; o; o >>= 1) s += __shfl_xor(s, o, 64);
        if (lane == 0) { stats[0] = mx; stats[1] = 1.f / s; }
    }
    __syncthreads();
    float mm = stats[0], inv = stats[1];
    if (tid < NP) {
        float a = __expf(es[tid] - mm) * inv;
        al_g[(long)b * NP + tid] = a;
        out_alpha[((long)b * NTM + t) * NP + tid] = a;
    }
    // xh extras (bf16): emb part and h part (2 elements each per thread)
    int cap = caps[b * NT + t];
    float2 ev = *(const float2*)(emb + (long)cap * 512 + tid * 2);
    unsigned int pk = (unsigned int)f2bf(ev.x) | ((unsigned int)f2bf(ev.y) << 16);
    *(unsigned int*)(xh + (long)b * 3072 + tid * 2) = pk;
    unsigned int hv = *(const unsigned int*)(h_bf + (long)b * DDEC + tid * 2);
    *(unsigned int*)(xh + (long)b * 3072 + 2560 + tid * 2) = hv;
}

// ---------------------------------------------------------------------------
// wx_kernel: xh[b][512+d] = bf16( (sum_p al[p]*enc[p][d]) * gate[d] )
// Grid (NB, 8) -> 256-col slices; 256 thr, 1 col each. Pruned by nt[t].
// ---------------------------------------------------------------------------
__global__ __launch_bounds__(256) void wx_kernel(
    const float* __restrict__ al_g,
    const float* __restrict__ adg,                // gate at [b][512+d]
    const float* __restrict__ enc, const int* __restrict__ order,
    const int* __restrict__ nt,
    unsigned short* __restrict__ xh, int t) {
    int b = blockIdx.x;
    if (b >= nt[t]) return;
    int d = blockIdx.y * 256 + threadIdx.x;   // < 2048
    __shared__ float al[NP];
    if (threadIdx.x < NP) al[threadIdx.x] = al_g[(long)b * NP + threadIdx.x];
    __syncthreads();
    const float* eb = enc + ((long)order[b] * NP) * DENC + d;
    float acc = 0.f;
#pragma unroll 4
    for (int p = 0; p < NP; ++p) acc += al[p] * eb[(long)p * DENC];
    float gate = adg[(long)b * 2560 + 512 + d];
    xh[(long)b * 3072 + 512 + d] = f2bf(acc * gate);
}

// LSTM pointwise: sum 3 K-chunk partials + bias, update c (fp32), h (bf16).
// grid (2, NB)
__global__ void lstm_kernel(const float* __restrict__ gp,
                            const float* __restrict__ bihh,
                            float* __restrict__ c,
                            unsigned short* __restrict__ h_bf,
                            const int* __restrict__ nt, int t) {
    int b = blockIdx.y;
    if (b >= nt[t]) return;
    int d = blockIdx.x * 256 + threadIdx.x;   // < 512
    const long S = (long)NB * 2048;
    const float* g = gp + ((long)b << 11);
    float ig = sigmoidf_(g[d]        + g[S + d]        + g[2*S + d]        + bihh[d]);
    float fg = sigmoidf_(g[512 + d]  + g[S + 512 + d]  + g[2*S + 512 + d]  + bihh[512 + d]);
    float gg = tanhf(    g[1024 + d] + g[S + 1024 + d] + g[2*S + 1024 + d] + bihh[1024 + d]);
    float og = sigmoidf_(g[1536 + d] + g[S + 1536 + d] + g[2*S + 1536 + d] + bihh[1536 + d]);
    long idx = (long)b * DDEC + d;
    float cn = fg * c[idx] + ig * gg;
    c[idx] = cn;
    h_bf[idx] = f2bf(og * tanhf(cn));
}

// ---------------------------------------------------------------------------
extern "C" void kernel_launch(void* const* d_in, const int* in_sizes, int n_in,
                              void* d_out, int out_size, void* d_ws, size_t ws_size,
                              hipStream_t stream) {
    const float* enc_out   = (const float*)d_in[0];
    const int*   enc_caps  = (const int*)d_in[1];
    const int*   len_caps  = (const int*)d_in[2];
    const float* emb       = (const float*)d_in[3];
    const float* W_enc_att = (const float*)d_in[4];
    const float* b_enc_att = (const float*)d_in[5];
    const float* W_dec_att = (const float*)d_in[6];
    const float* b_dec_att = (const float*)d_in[7];
    const float* W_att     = (const float*)d_in[8];
    const float* b_att     = (const float*)d_in[9];
    const float* W_init_h  = (const float*)d_in[10];
    const float* b_init_h  = (const float*)d_in[11];
    const float* W_init_c  = (const float*)d_in[12];
    const float* b_init_c  = (const float*)d_in[13];
    const float* W_ih      = (const float*)d_in[14];
    const float* b_ih      = (const float*)d_in[15];
    const float* W_hh      = (const float*)d_in[16];
    const float* b_hh      = (const float*)d_in[17];
    const float* W_fbeta   = (const float*)d_in[18];
    const float* b_fbeta   = (const float*)d_in[19];
    const float* W_fc      = (const float*)d_in[20];
    const float* b_fc      = (const float*)d_in[21];

    float* out        = (float*)d_out;
    float* out_caps   = out;
    float* out_lendec = out + 3840;
    float* out_pred   = out + 3968;
    float* out_alpha  = out + 3968 + 37120000;
    float* out_order  = out + 3968 + 37120000 + 727552;

    char*  wsb = (char*)d_ws;
    size_t off = 0;
    auto alloc = [&](size_t bytes) -> void* {
        void* p = wsb + off;
        off += (bytes + 255) & ~(size_t)255;
        return p;
    };
    int*   order_ws = (int*)alloc(NB * 4);
    int*   nt_ws    = (int*)alloc(NTM * 4);
    int*   caps_ws  = (int*)alloc(NB * NT * 4);
    int*   rowmap   = (int*)alloc((size_t)NB * NP * 4);
    float* mu       = (float*)alloc((size_t)NB * DENC * 4);
    float* c        = (float*)alloc((size_t)NB * DDEC * 4);
    float* adg      = (float*)alloc((size_t)NB * 2560 * 4);
    float* al_g     = (float*)alloc((size_t)NB * NP * 4);
    float* gates    = (float*)alloc((size_t)3 * NB * 2048 * 4);   // 3 K-chunk partials
    unsigned short* h_bf = (unsigned short*)alloc((size_t)NB * DDEC * 2);
    unsigned short* xh   = (unsigned short*)alloc((size_t)NB * 3072 * 2);
    unsigned short* att_enc_bf = (unsigned short*)alloc((size_t)NB * NP * 512 * 2);
    unsigned short* Wq_enc  = (unsigned short*)alloc((size_t)512 * 2048 * 2);
    unsigned short* Wq_init = (unsigned short*)alloc((size_t)1024 * 2048 * 2);
    unsigned short* Wq_adg  = (unsigned short*)alloc((size_t)2560 * 512 * 2);
    unsigned short* Wq_ihh  = (unsigned short*)alloc((size_t)2048 * 3072 * 2);
    unsigned short* Wq_fc   = (unsigned short*)alloc((size_t)NV * 512 * 2);
    float* bihh = (float*)alloc(2048 * 4);

    // ---- prologue ----
    sort_kernel<<<1, NB, 0, stream>>>(len_caps, enc_caps, out_caps, out_lendec,
                                      out_order, order_ws, nt_ws, caps_ws);
    fill_zero4<<<36960, 256, 0, stream>>>((float4*)out_pred, 9461888);  // preds+alphas
    rowmap_kernel<<<98, 256, 0, stream>>>(order_ws, rowmap);
    mu_kernel<<<dim3(NB, DENC / 256), 256, 0, stream>>>(enc_out, order_ws, mu);

    conv_bf<<<(512 * 2048) / 256, 256, 0, stream>>>(W_enc_att, Wq_enc, 512 * 2048);
    conv_bf<<<(512 * 2048) / 256, 256, 0, stream>>>(W_init_h, Wq_init, 512 * 2048);
    conv_bf<<<(512 * 2048) / 256, 256, 0, stream>>>(W_init_c, Wq_init + (size_t)512 * 2048, 512 * 2048);
    conv_bf<<<(512 * 512) / 256, 256, 0, stream>>>(W_dec_att, Wq_adg, 512 * 512);
    conv_bf<<<(2048 * 512) / 256, 256, 0, stream>>>(W_fbeta, Wq_adg + (size_t)512 * 512, 2048 * 512);
    kconcat_ihh<<<dim3(12, 2048), 256, 0, stream>>>(W_ih, W_hh, Wq_ihh);
    conv_bf<<<(NV * 512) / 256, 256, 0, stream>>>(W_fc, Wq_fc, NV * 512);
    bias_add2<<<8, 256, 0, stream>>>(b_ih, b_hh, bihh, 2048);

    // h|c init: A=mu, W=Wq_init [1024][2048], split at 512.
    // seg0 -> h_bf (bf16), seg1 -> c (fp32)
    gemm_mfma<<<dim3(8, 2), 256, 0, stream>>>(
        mu, DENC, nullptr, Wq_init, DENC,
        b_init_h, b_init_c, 512,
        nullptr, DDEC, c, DDEC, h_bf, 0, 0,
        NB, 1024, DENC, nullptr, 0, 0, 0);

    // att_enc (bf16 out): A=enc via rowmap, W=Wq_enc [512][2048]
    gemm_mfma<<<dim3(4, 392), 256, 0, stream>>>(
        enc_out, DENC, rowmap, Wq_enc, DENC,
        b_enc_att, nullptr, 512,
        nullptr, 512, nullptr, 0, att_enc_bf, 0, 0,
        NB * NP, 512, DENC, nullptr, 0, 0, 0);

    // ---- time loop ----
    for (int t = 0; t < NTM; ++t) {
        // adg = [att_dec | sigmoid(gate)]: A=h_bf, W=Wq_adg [2560][512]
        gemm_mfma<<<dim3(20, 2), 256, 0, stream>>>(
            (const float*)h_bf, DDEC, nullptr, Wq_adg, DDEC,
            b_dec_att, b_fbeta, 512,
            adg, 2560, adg + 512, 2560, nullptr, 0, 1,
            NB, 2560, DDEC, nt_ws, t, 0, 1);
        // e + softmax -> al_g/out_alpha; also fills xh emb & h parts (bf16)
        alpha_kernel<<<NB, 256, 0, stream>>>(
            att_enc_bf, adg, W_att, b_att, emb, caps_ws, h_bf, nt_ws,
            al_g, out_alpha, xh, t);
        // xh middle: weighted*gate (bf16), 8-way column split
        wx_kernel<<<dim3(NB, 8), 256, 0, stream>>>(
            al_g, adg, enc_out, order_ws, nt_ws, xh, t);
        // gates partials = xh @ Wq_ihh^T, split-K x3 (K=1024 per chunk)
        gemm_mfma<<<dim3(16, 2, 3), 256, 0, stream>>>(
            (const float*)xh, 3072, nullptr, Wq_ihh, 3072,
            nullptr, nullptr, 2048,
            gates, 2048, nullptr, 0, nullptr, 0, 0,
            NB, 2048, 1024, nt_ws, t, (long)NB * 2048, 1);
        // LSTM pointwise (sums partials + bias; c fp32, h bf16)
        lstm_kernel<<<dim3(2, NB), 256, 0, stream>>>(gates, bihh, c, h_bf, nt_ws, t);
        // preds = h_bf @ Wq_fc^T (active rows only; rest pre-zeroed)
        gemm_mfma<<<dim3(79, 2), 256, 0, stream>>>(
            (const float*)h_bf, DDEC, nullptr, Wq_fc, DDEC,
            b_fc, nullptr, NV,
            out_pred + (long)t * NV, (long)NTM * NV, nullptr, 0, nullptr, 0, 0,
            NB, NV, DDEC, nt_ws, t, 0, 1);
    }
}